// Round 9
// baseline (1574.753 us; speedup 1.0000x reference)
//
#include <hip/hip_runtime.h>
#include <hip/hip_bf16.h>
#include <stdint.h>

// DbrxExpertGLU: down = (silu(x@w1^T) * (x@v1^T)) @ w2
// T=4096, H=4096, F=14336. fp32 in/out; bf16 MFMA compute.
// R9: decompose — gate/up/down are three instantiations of ONE 256x256 8-phase
// GEMM template. up256: plain bf16-out GEMM. gate256f: same GEMM, epilogue
// loads u from upb and writes silu(g)*u. All three become profiler-visible.
// ws buffers: single-writer, write-before-read, never rewritten.
#define TOKENS 4096
#define HIDDEN 4096
#define FFN    14336

typedef __attribute__((ext_vector_type(8))) short bf16x8;
typedef __attribute__((ext_vector_type(4))) float f32x4;
typedef __attribute__((ext_vector_type(8))) unsigned short u16x8;

typedef __attribute__((address_space(3))) void lds_void_t;
typedef const __attribute__((address_space(1))) void gbl_void_t;

static __device__ __forceinline__ unsigned short f2b(float f) {
  union { float f; unsigned int u; } v; v.f = f;
  unsigned int u = v.u;
  return (unsigned short)((u + 0x7FFFu + ((u >> 16) & 1u)) >> 16);  // RNE
}
static __device__ __forceinline__ float b2f(unsigned short b) {
  union { unsigned int u; float f; } v; v.u = ((unsigned int)b) << 16;
  return v.f;
}

// ---------------- fp32 -> bf16 convert ----------------
__global__ void cvt_kernel(const float* __restrict__ in, unsigned short* __restrict__ out, long n) {
  long idx = (long)blockIdx.x * blockDim.x + threadIdx.x;
  long stride = (long)gridDim.x * blockDim.x;
  for (long i = idx * 4; i < n; i += stride * 4) {
    const float4 v = *reinterpret_cast<const float4*>(in + i);
    ushort4 o;
    o.x = f2b(v.x); o.y = f2b(v.y); o.z = f2b(v.z); o.w = f2b(v.w);
    *reinterpret_cast<ushort4*>(out + i) = o;
  }
}

// ------- w2 [F][H] fp32 -> w2t [H][F] bf16 -------
__global__ void transpose_cvt_kernel(const float* __restrict__ in, unsigned short* __restrict__ out) {
  __shared__ float tile[64][65];
  const int f0 = blockIdx.x * 64;
  const int h0 = blockIdx.y * 64;
  const int t = threadIdx.x;
  const int rcol = (t & 15) * 4;
  const int rrow = t >> 4;
#pragma unroll
  for (int it = 0; it < 4; ++it) {
    int r = rrow + it * 16;
    const float4 v = *reinterpret_cast<const float4*>(in + (long)(f0 + r) * HIDDEN + h0 + rcol);
    tile[r][rcol] = v.x; tile[r][rcol + 1] = v.y; tile[r][rcol + 2] = v.z; tile[r][rcol + 3] = v.w;
  }
  __syncthreads();
  const int wrow = t >> 2;
  const int wc = (t & 3) * 16;
  u16x8 lo, hi;
#pragma unroll
  for (int j = 0; j < 8; ++j) lo[j] = f2b(tile[wc + j][wrow]);
#pragma unroll
  for (int j = 0; j < 8; ++j) hi[j] = f2b(tile[wc + 8 + j][wrow]);
  u16x8* dst = reinterpret_cast<u16x8*>(out + (long)(h0 + wrow) * FFN + f0 + wc);
  dst[0] = lo; dst[1] = hi;
}

#define MFMA16(a, b, c) __builtin_amdgcn_mfma_f32_16x16x32_bf16((a), (b), (c), 0, 0, 0)
#define SBAR()  __builtin_amdgcn_s_barrier()
#define SCHED0() __builtin_amdgcn_sched_barrier(0)

// ============ unified 256x256 BT GEMM, 8-phase counted-vmcnt ============
// A[.. ][LDK] bf16, B[..][LDK] bf16 (B rows = output cols). NT = LDK/64 K-tiles.
// EPI: 0 = store bf16, 1 = store fp32, 2 = silu-fuse (Out16 = silu(acc)*Up).
template <int LDK, int NT, int LDN, int EPI>
__global__ __launch_bounds__(512, 2)
void gemm256_kernel(const unsigned short* __restrict__ A,
                    const unsigned short* __restrict__ B,
                    void* __restrict__ OutV,
                    const unsigned short* __restrict__ Up) {
  __shared__ unsigned short sh[65536];
  const int tid = threadIdx.x, lane = tid & 63, wid = tid >> 6;
  const int wm = wid >> 2, wn = wid & 3;
  const int bm = blockIdx.x & 15;   // T-tile fastest (16 blocks share one B panel)
  const int bn = blockIdx.x >> 4;
  const int sr = tid >> 3;
  const int scb = (((tid & 7) ^ (sr & 7)) << 4);
  const int l15 = lane & 15;
  const int cb0 = (((lane >> 4) * 16) ^ ((lane & 7) << 4));
  const int cb1 = ((64 + (lane >> 4) * 16) ^ ((lane & 7) << 4));

  const unsigned short* Ap = A + (long)(bm * 256) * LDK;
  const unsigned short* Bp = B + (long)(bn * 256) * LDK;

  f32x4 acc[8][4] = {};

  auto STAGE = [&](int kind, int h, int buf, int t) {  // 128 rows, 2 gloads/thread
    const unsigned short* src = (kind ? Bp : Ap) + (long)(h * 128 + sr) * LDK + t * 64 + (scb >> 1);
    unsigned short* dst = sh + buf * 32768 + kind * 16384 + h * 8192 + tid * 8;
    __builtin_amdgcn_global_load_lds((gbl_void_t*)src, (lds_void_t*)dst, 16, 0, 0);
    __builtin_amdgcn_global_load_lds((gbl_void_t*)(src + 64L * LDK), (lds_void_t*)(dst + 4096), 16, 0, 0);
  };
  auto LDA8 = [&](bf16x8* a, int buf, int cb) {
    const char* base = (const char*)sh + buf * 65536 + wm * 16384 + l15 * 128 + cb;
#pragma unroll
    for (int m = 0; m < 8; ++m) a[m] = *(const bf16x8*)(base + m * 2048);
  };
  auto LDB2 = [&](bf16x8* b, int buf, int cb, int np) {
    const char* base = (const char*)sh + buf * 65536 + 32768 + (wn >> 1) * 16384 +
                       ((wn & 1) * 64 + l15) * 128 + cb;
    b[2 * np]     = *(const bf16x8*)(base + (2 * np) * 2048);
    b[2 * np + 1] = *(const bf16x8*)(base + (2 * np + 1) * 2048);
  };

  STAGE(0, 0, 0, 0); STAGE(0, 1, 0, 0); STAGE(1, 0, 0, 0); STAGE(1, 1, 0, 0);

  bf16x8 a[8], b[4];
  for (int t = 0; t < NT; ++t) {
    const int cur = t & 1, nxt = cur ^ 1;
    const bool pre = (t + 1 < NT);
    // P0: stage B(t+1); gate vmcnt(4); barrier; read A8+B2 kk0; MFMA n01 kk0
    if (pre) { STAGE(1, 0, nxt, t + 1); STAGE(1, 1, nxt, t + 1);
               asm volatile("s_waitcnt vmcnt(4)" ::: "memory"); }
    else     { asm volatile("s_waitcnt vmcnt(0)" ::: "memory"); }
    SBAR(); SCHED0();
    LDA8(a, cur, cb0); LDB2(b, cur, cb0, 0);
    __builtin_amdgcn_s_setprio(1);
#pragma unroll
    for (int m = 0; m < 8; ++m) {
      acc[m][0] = MFMA16(a[m], b[0], acc[m][0]);
      acc[m][1] = MFMA16(a[m], b[1], acc[m][1]);
    }
    __builtin_amdgcn_s_setprio(0);
    SCHED0(); SBAR();
    // P1: read B kk0 np1 EARLY; stage A(t+1); barrier; MFMA n23 kk0
    LDB2(b, cur, cb0, 1);
    if (pre) { STAGE(0, 0, nxt, t + 1); STAGE(0, 1, nxt, t + 1); }
    SCHED0(); SBAR();
    __builtin_amdgcn_s_setprio(1);
#pragma unroll
    for (int m = 0; m < 8; ++m) {
      acc[m][2] = MFMA16(a[m], b[2], acc[m][2]);
      acc[m][3] = MFMA16(a[m], b[3], acc[m][3]);
    }
    __builtin_amdgcn_s_setprio(0);
    SCHED0(); SBAR();
    // P2: read A8+B2 kk1 np0 EARLY; barrier; MFMA n01 kk1
    LDA8(a, cur, cb1); LDB2(b, cur, cb1, 0);
    SCHED0(); SBAR();
    __builtin_amdgcn_s_setprio(1);
#pragma unroll
    for (int m = 0; m < 8; ++m) {
      acc[m][0] = MFMA16(a[m], b[0], acc[m][0]);
      acc[m][1] = MFMA16(a[m], b[1], acc[m][1]);
    }
    __builtin_amdgcn_s_setprio(0);
    SCHED0(); SBAR();
    // P3: read B kk1 np1 EARLY; barrier; MFMA n23 kk1
    LDB2(b, cur, cb1, 1);
    SCHED0(); SBAR();
    __builtin_amdgcn_s_setprio(1);
#pragma unroll
    for (int m = 0; m < 8; ++m) {
      acc[m][2] = MFMA16(a[m], b[2], acc[m][2]);
      acc[m][3] = MFMA16(a[m], b[3], acc[m][3]);
    }
    __builtin_amdgcn_s_setprio(0);
    SCHED0(); SBAR();
  }
  // ---- epilogue. C/D map: col=lane&15, row=(lane>>4)*4+r (m89)
  const int r0 = (lane >> 4) * 4;
#pragma unroll
  for (int m = 0; m < 8; ++m)
#pragma unroll
    for (int n = 0; n < 4; ++n) {
      const long rowb = bm * 256 + wm * 128 + m * 16 + r0;
      const long col = bn * 256 + wn * 64 + n * 16 + l15;
#pragma unroll
      for (int r = 0; r < 4; ++r) {
        if (EPI == 1) {
          ((float*)OutV)[(rowb + r) * (long)LDN + col] = acc[m][n][r];
        } else if (EPI == 0) {
          ((unsigned short*)OutV)[(rowb + r) * (long)LDN + col] = f2b(acc[m][n][r]);
        } else {
          const float u = b2f(Up[(rowb + r) * (long)LDN + col]);
          const float g = acc[m][n][r];
          const float s = g / (1.0f + __expf(-g));
          ((unsigned short*)OutV)[(rowb + r) * (long)LDN + col] = f2b(s * u);
        }
      }
    }
}

// ============ R8 fused gate/up (fallback when ws < split layout) ============
__global__ __launch_bounds__(512, 2)
void gateup256b_kernel(const unsigned short* __restrict__ X,
                       const unsigned short* __restrict__ W1,
                       const unsigned short* __restrict__ V1,
                       unsigned short* __restrict__ Inter) {
  __shared__ unsigned short sh[65536];
  const int tid = threadIdx.x, lane = tid & 63, wid = tid >> 6;
  const int wm = wid >> 2, wn = wid & 3;
  const int bm = blockIdx.x & 15;
  const int bn = blockIdx.x >> 4;
  const int sr = tid >> 3;
  const int scb = (((tid & 7) ^ (sr & 7)) << 4);
  const int l15 = lane & 15;
  const int cb0 = (((lane >> 4) * 16) ^ ((lane & 7) << 4));
  const int cb1 = ((64 + (lane >> 4) * 16) ^ ((lane & 7) << 4));

  const unsigned short* Ap = X  + (long)(bm * 256) * HIDDEN;
  const unsigned short* Wp = W1 + (long)(bn * 128) * HIDDEN;
  const unsigned short* Vp = V1 + (long)(bn * 128) * HIDDEN;

  f32x4 acc[8][4] = {};

  auto STAGE = [&](int kind, int h, int buf, int t) {
    const unsigned short* src;
    if (kind == 0) src = Ap + (long)(h * 128 + sr) * HIDDEN + t * 64 + (scb >> 1);
    else           src = (h ? Vp : Wp) + (long)sr * HIDDEN + t * 64 + (scb >> 1);
    unsigned short* dst = sh + buf * 32768 + kind * 16384 + h * 8192 + tid * 8;
    __builtin_amdgcn_global_load_lds((gbl_void_t*)src, (lds_void_t*)dst, 16, 0, 0);
    __builtin_amdgcn_global_load_lds((gbl_void_t*)(src + 64L * HIDDEN), (lds_void_t*)(dst + 4096), 16, 0, 0);
  };
  auto LDA8 = [&](bf16x8* a, int buf, int cb) {
    const char* base = (const char*)sh + buf * 65536 + wm * 16384 + l15 * 128 + cb;
#pragma unroll
    for (int m = 0; m < 8; ++m) a[m] = *(const bf16x8*)(base + m * 2048);
  };
  auto LDB2 = [&](bf16x8* b, int buf, int cb, int np) {
    const char* base = (const char*)sh + buf * 65536 + 32768 + (wn >> 1) * 16384 +
                       ((wn & 1) * 64 + l15) * 128 + cb;
    b[2 * np]     = *(const bf16x8*)(base + (2 * np) * 2048);
    b[2 * np + 1] = *(const bf16x8*)(base + (2 * np + 1) * 2048);
  };

  STAGE(0, 0, 0, 0); STAGE(0, 1, 0, 0); STAGE(1, 0, 0, 0); STAGE(1, 1, 0, 0);

  bf16x8 a[8], b[4];
  const int NT = HIDDEN / 64;
  for (int t = 0; t < NT; ++t) {
    const int cur = t & 1, nxt = cur ^ 1;
    const bool pre = (t + 1 < NT);
    if (pre) { STAGE(1, 0, nxt, t + 1); STAGE(1, 1, nxt, t + 1);
               asm volatile("s_waitcnt vmcnt(4)" ::: "memory"); }
    else     { asm volatile("s_waitcnt vmcnt(0)" ::: "memory"); }
    SBAR(); SCHED0();
    LDA8(a, cur, cb0); LDB2(b, cur, cb0, 0);
    __builtin_amdgcn_s_setprio(1);
#pragma unroll
    for (int m = 0; m < 8; ++m) {
      acc[m][0] = MFMA16(a[m], b[0], acc[m][0]);
      acc[m][1] = MFMA16(a[m], b[1], acc[m][1]);
    }
    __builtin_amdgcn_s_setprio(0);
    SCHED0(); SBAR();
    LDB2(b, cur, cb0, 1);
    if (pre) { STAGE(0, 0, nxt, t + 1); STAGE(0, 1, nxt, t + 1); }
    SCHED0(); SBAR();
    __builtin_amdgcn_s_setprio(1);
#pragma unroll
    for (int m = 0; m < 8; ++m) {
      acc[m][2] = MFMA16(a[m], b[2], acc[m][2]);
      acc[m][3] = MFMA16(a[m], b[3], acc[m][3]);
    }
    __builtin_amdgcn_s_setprio(0);
    SCHED0(); SBAR();
    LDA8(a, cur, cb1); LDB2(b, cur, cb1, 0);
    SCHED0(); SBAR();
    __builtin_amdgcn_s_setprio(1);
#pragma unroll
    for (int m = 0; m < 8; ++m) {
      acc[m][0] = MFMA16(a[m], b[0], acc[m][0]);
      acc[m][1] = MFMA16(a[m], b[1], acc[m][1]);
    }
    __builtin_amdgcn_s_setprio(0);
    SCHED0(); SBAR();
    LDB2(b, cur, cb1, 1);
    SCHED0(); SBAR();
    __builtin_amdgcn_s_setprio(1);
#pragma unroll
    for (int m = 0; m < 8; ++m) {
      acc[m][2] = MFMA16(a[m], b[2], acc[m][2]);
      acc[m][3] = MFMA16(a[m], b[3], acc[m][3]);
    }
    __builtin_amdgcn_s_setprio(0);
    SCHED0(); SBAR();
  }
  __syncthreads();
  if (wn >= 2) {
#pragma unroll
    for (int m = 0; m < 8; ++m)
#pragma unroll
      for (int n = 0; n < 4; ++n) {
        ushort4 p;
        p.x = f2b(acc[m][n][0]); p.y = f2b(acc[m][n][1]);
        p.z = f2b(acc[m][n][2]); p.w = f2b(acc[m][n][3]);
        const int idx = ((((wm * 2 + (wn & 1)) * 8 + m) * 4 + n) * 64 + lane) * 4;
        *reinterpret_cast<ushort4*>(&sh[idx]) = p;
      }
  }
  __syncthreads();
  if (wn < 2) {
    const int r0 = (lane >> 4) * 4;
#pragma unroll
    for (int m = 0; m < 8; ++m)
#pragma unroll
      for (int n = 0; n < 4; ++n) {
        const int idx = ((((wm * 2 + wn) * 8 + m) * 4 + n) * 64 + lane) * 4;
        const ushort4 p = *reinterpret_cast<const ushort4*>(&sh[idx]);
        const float uu[4] = { b2f(p.x), b2f(p.y), b2f(p.z), b2f(p.w) };
        const int row = bm * 256 + wm * 128 + m * 16 + r0;
        const int col = bn * 128 + wn * 64 + n * 16 + l15;
#pragma unroll
        for (int r = 0; r < 4; ++r) {
          const float g = acc[m][n][r];
          const float s = g / (1.0f + __expf(-g));
          Inter[(long)(row + r) * FFN + col] = f2b(s * uu[r]);
        }
      }
  }
}

extern "C" void kernel_launch(void* const* d_in, const int* in_sizes, int n_in,
                              void* d_out, int out_size, void* d_ws, size_t ws_size,
                              hipStream_t stream) {
  const float* x  = (const float*)d_in[0];
  const float* w1 = (const float*)d_in[1];
  const float* v1 = (const float*)d_in[2];
  const float* w2 = (const float*)d_in[3];
  float* out = (float*)d_out;

  // SPLIT layout: xb 33.5M | w1b 117.4M | v1b 117.4M | upb 117.4M | interb 117.4M | w2t 117.4M
  const size_t REQ_SPLIT = 620756992UL;
  // FUSED (R8) layout: xb | w1b | v1b | interb | w2t
  const size_t REQ_FUSED = 503316480UL;
  if (ws_size < REQ_FUSED) return;
  char* ws = (char*)d_ws;
  unsigned short* xb  = (unsigned short*)(ws);
  unsigned short* w1b = (unsigned short*)(ws + 33554432L);
  unsigned short* v1b = (unsigned short*)(ws + 150994944L);

  hipLaunchKernelGGL(cvt_kernel, dim3(2048), dim3(256), 0, stream, x,  xb,  (long)TOKENS * HIDDEN);
  hipLaunchKernelGGL(cvt_kernel, dim3(2048), dim3(256), 0, stream, w1, w1b, (long)FFN * HIDDEN);
  hipLaunchKernelGGL(cvt_kernel, dim3(2048), dim3(256), 0, stream, v1, v1b, (long)FFN * HIDDEN);

  if (ws_size >= REQ_SPLIT) {
    unsigned short* upb    = (unsigned short*)(ws + 268435456L);
    unsigned short* interb = (unsigned short*)(ws + 385875968L);
    unsigned short* w2tb   = (unsigned short*)(ws + 503316480L);
    hipLaunchKernelGGL(transpose_cvt_kernel, dim3(FFN / 64, HIDDEN / 64), dim3(256), 0, stream, w2, w2tb);
    // up = x @ v1^T  (plain bf16-out GEMM)
    hipLaunchKernelGGL((gemm256_kernel<HIDDEN, HIDDEN / 64, FFN, 0>),
                       dim3((TOKENS / 256) * (FFN / 256)), dim3(512), 0, stream,
                       xb, v1b, (void*)upb, (const unsigned short*)nullptr);
    // inter = silu(x @ w1^T) * up  (fused epilogue)
    hipLaunchKernelGGL((gemm256_kernel<HIDDEN, HIDDEN / 64, FFN, 2>),
                       dim3((TOKENS / 256) * (FFN / 256)), dim3(512), 0, stream,
                       xb, w1b, (void*)interb, upb);
    // out = inter @ w2t^T  (fp32 out)
    hipLaunchKernelGGL((gemm256_kernel<FFN, FFN / 64, HIDDEN, 1>),
                       dim3((TOKENS / 256) * (HIDDEN / 256)), dim3(512), 0, stream,
                       interb, w2tb, (void*)out, (const unsigned short*)nullptr);
  } else {
    unsigned short* interb = (unsigned short*)(ws + 268435456L);
    unsigned short* w2tb   = (unsigned short*)(ws + 385875968L);
    hipLaunchKernelGGL(transpose_cvt_kernel, dim3(FFN / 64, HIDDEN / 64), dim3(256), 0, stream, w2, w2tb);
    hipLaunchKernelGGL(gateup256b_kernel, dim3((TOKENS / 256) * (FFN / 128)), dim3(512), 0, stream,
                       xb, w1b, v1b, interb);
    hipLaunchKernelGGL((gemm256_kernel<FFN, FFN / 64, HIDDEN, 1>),
                       dim3((TOKENS / 256) * (HIDDEN / 256)), dim3(512), 0, stream,
                       interb, w2tb, (void*)out, (const unsigned short*)nullptr);
  }
}

// Round 10
// 1431.624 us; speedup vs baseline: 1.1000x; 1.1000x over previous
//
#include <hip/hip_runtime.h>
#include <hip/hip_bf16.h>
#include <stdint.h>

// DbrxExpertGLU: down = (silu(x@w1^T) * (x@v1^T)) @ w2
// T=4096, H=4096, F=14336. fp32 in/out; bf16 MFMA compute.
// R10 = R6 (best, 1426us) + chunked XCD swizzle on both 256-GEMMs:
// consecutive tile-indices land on the SAME XCD so panel-sharing blocks hit
// one L2 (HW: XCD = blockIdx % 8). Grids 1792 and 256, both %8==0 (bijective).
#define TOKENS 4096
#define HIDDEN 4096
#define FFN    14336

typedef __attribute__((ext_vector_type(8))) short bf16x8;
typedef __attribute__((ext_vector_type(4))) float f32x4;
typedef __attribute__((ext_vector_type(8))) unsigned short u16x8;

typedef __attribute__((address_space(3))) void lds_void_t;
typedef const __attribute__((address_space(1))) void gbl_void_t;

static __device__ __forceinline__ unsigned short f2b(float f) {
  union { float f; unsigned int u; } v; v.f = f;
  unsigned int u = v.u;
  return (unsigned short)((u + 0x7FFFu + ((u >> 16) & 1u)) >> 16);  // RNE
}

// ---------------- fp32 -> bf16 convert ----------------
__global__ void cvt_kernel(const float* __restrict__ in, unsigned short* __restrict__ out, long n) {
  long idx = (long)blockIdx.x * blockDim.x + threadIdx.x;
  long stride = (long)gridDim.x * blockDim.x;
  for (long i = idx * 4; i < n; i += stride * 4) {
    const float4 v = *reinterpret_cast<const float4*>(in + i);
    ushort4 o;
    o.x = f2b(v.x); o.y = f2b(v.y); o.z = f2b(v.z); o.w = f2b(v.w);
    *reinterpret_cast<ushort4*>(out + i) = o;
  }
}

// ------- w2 [F][H] fp32 -> w2t [H][F] bf16 -------
__global__ void transpose_cvt_kernel(const float* __restrict__ in, unsigned short* __restrict__ out) {
  __shared__ float tile[64][65];
  const int f0 = blockIdx.x * 64;
  const int h0 = blockIdx.y * 64;
  const int t = threadIdx.x;
  const int rcol = (t & 15) * 4;
  const int rrow = t >> 4;
#pragma unroll
  for (int it = 0; it < 4; ++it) {
    int r = rrow + it * 16;
    const float4 v = *reinterpret_cast<const float4*>(in + (long)(f0 + r) * HIDDEN + h0 + rcol);
    tile[r][rcol] = v.x; tile[r][rcol + 1] = v.y; tile[r][rcol + 2] = v.z; tile[r][rcol + 3] = v.w;
  }
  __syncthreads();
  const int wrow = t >> 2;
  const int wc = (t & 3) * 16;
  u16x8 lo, hi;
#pragma unroll
  for (int j = 0; j < 8; ++j) lo[j] = f2b(tile[wc + j][wrow]);
#pragma unroll
  for (int j = 0; j < 8; ++j) hi[j] = f2b(tile[wc + 8 + j][wrow]);
  u16x8* dst = reinterpret_cast<u16x8*>(out + (long)(h0 + wrow) * FFN + f0 + wc);
  dst[0] = lo; dst[1] = hi;
}

#define MFMA16(a, b, c) __builtin_amdgcn_mfma_f32_16x16x32_bf16((a), (b), (c), 0, 0, 0)
#define SBAR()  __builtin_amdgcn_s_barrier()
#define SCHED0() __builtin_amdgcn_sched_barrier(0)

// Chunked XCD swizzle: HW assigns XCD = blockIdx % 8; remap so each XCD gets a
// CONTIGUOUS tile range (panel-sharing tiles colocate on one L2). nwg % 8 == 0.
static __device__ __forceinline__ int xcd_chunk(int bid, int nwg) {
  return (bid & 7) * (nwg >> 3) + (bid >> 3);
}

// ============ fused gate/up, 8-phase: BM=256(T) x BN=128(F), BK=64, 8 waves ============
// LDS per buf (64KB): A[256][64] @0 | W[128][64] @32K | V[128][64] @48K.  x2 dbuf = 128KB.
__global__ __launch_bounds__(512, 2)
void gateup256_kernel(const unsigned short* __restrict__ X,
                      const unsigned short* __restrict__ W1,
                      const unsigned short* __restrict__ V1,
                      unsigned short* __restrict__ Inter) {
  __shared__ unsigned short sh[65536];  // 128 KB
  const int tid = threadIdx.x, lane = tid & 63, wid = tid >> 6;
  const int wm = wid >> 2, wn = wid & 3;
  const int swz = xcd_chunk(blockIdx.x, (TOKENS / 256) * (FFN / 128));  // 1792
  const int bm = swz & 15;   // T-tile fastest within XCD chunk
  const int bn = swz >> 4;   // F-tile
  const int sr = tid >> 3;                                   // staging row 0..63
  const int scb = (((tid & 7) ^ (sr & 7)) << 4);             // pre-swizzled src byte-col
  const int l15 = lane & 15;
  const int cb0 = (((lane >> 4) * 16) ^ ((lane & 7) << 4));  // frag byte-col, kk=0
  const int cb1 = ((64 + (lane >> 4) * 16) ^ ((lane & 7) << 4));

  const unsigned short* Ap = X  + (long)(bm * 256) * HIDDEN;
  const unsigned short* Wp = W1 + (long)(bn * 128) * HIDDEN;
  const unsigned short* Vp = V1 + (long)(bn * 128) * HIDDEN;

  f32x4 accg[8][2] = {};
  f32x4 accu[8][2] = {};

  auto STA = [&](int u, int buf, int t) {
    const unsigned short* src = Ap + (long)(u * 64 + sr) * HIDDEN + t * 64 + (scb >> 1);
    unsigned short* dst = sh + buf * 32768 + u * 4096 + tid * 8;
    __builtin_amdgcn_global_load_lds((gbl_void_t*)src, (lds_void_t*)dst, 16, 0, 0);
  };
  auto STW = [&](int u, int buf, int t) {
    const unsigned short* src = Wp + (long)(u * 64 + sr) * HIDDEN + t * 64 + (scb >> 1);
    unsigned short* dst = sh + buf * 32768 + 16384 + u * 4096 + tid * 8;
    __builtin_amdgcn_global_load_lds((gbl_void_t*)src, (lds_void_t*)dst, 16, 0, 0);
  };
  auto STV = [&](int u, int buf, int t) {
    const unsigned short* src = Vp + (long)(u * 64 + sr) * HIDDEN + t * 64 + (scb >> 1);
    unsigned short* dst = sh + buf * 32768 + 24576 + u * 4096 + tid * 8;
    __builtin_amdgcn_global_load_lds((gbl_void_t*)src, (lds_void_t*)dst, 16, 0, 0);
  };
  auto LDA8 = [&](bf16x8* a, int buf, int cb) {
    const char* base = (const char*)sh + buf * 65536 + wm * 16384 + l15 * 128 + cb;
#pragma unroll
    for (int m = 0; m < 8; ++m) a[m] = *(const bf16x8*)(base + m * 2048);
  };
  auto LDW2 = [&](bf16x8* w, int buf, int cb) {
    const char* base = (const char*)sh + buf * 65536 + 32768 + (wn * 32 + l15) * 128 + cb;
    w[0] = *(const bf16x8*)(base);
    w[1] = *(const bf16x8*)(base + 2048);
  };
  auto LDV2 = [&](bf16x8* v, int buf, int cb) {
    const char* base = (const char*)sh + buf * 65536 + 49152 + (wn * 32 + l15) * 128 + cb;
    v[0] = *(const bf16x8*)(base);
    v[1] = *(const bf16x8*)(base + 2048);
  };

  STA(0, 0, 0); STA(1, 0, 0); STA(2, 0, 0); STA(3, 0, 0);
  STW(0, 0, 0); STW(1, 0, 0); STV(0, 0, 0); STV(1, 0, 0);

  bf16x8 a[8], w[2], v[2];
  const int NT = HIDDEN / 64;  // 64
  for (int t = 0; t < NT; ++t) {
    const int cur = t & 1, nxt = cur ^ 1;
    const bool pre = (t + 1 < NT);
    // P0: prefetch W+V(t+1) (streamed, 4-phase lead); gate vmcnt(4); kk0 x W
    if (pre) { STW(0, nxt, t + 1); STW(1, nxt, t + 1);
               STV(0, nxt, t + 1); STV(1, nxt, t + 1);
               asm volatile("s_waitcnt vmcnt(4)" ::: "memory"); }
    else     { asm volatile("s_waitcnt vmcnt(0)" ::: "memory"); }
    SBAR(); SCHED0();
    LDA8(a, cur, cb0); LDW2(w, cur, cb0);
    __builtin_amdgcn_s_setprio(1);
#pragma unroll
    for (int m = 0; m < 8; ++m) {
      accg[m][0] = MFMA16(a[m], w[0], accg[m][0]);
      accg[m][1] = MFMA16(a[m], w[1], accg[m][1]);
    }
    __builtin_amdgcn_s_setprio(0);
    SCHED0();
    asm volatile("s_waitcnt lgkmcnt(0)" ::: "memory");
    SBAR();
    // P1: prefetch A(t+1); kk0 x V
    if (pre) { STA(0, nxt, t + 1); STA(1, nxt, t + 1);
               STA(2, nxt, t + 1); STA(3, nxt, t + 1); }
    SCHED0();
    LDV2(v, cur, cb0);
    __builtin_amdgcn_s_setprio(1);
#pragma unroll
    for (int m = 0; m < 8; ++m) {
      accu[m][0] = MFMA16(a[m], v[0], accu[m][0]);
      accu[m][1] = MFMA16(a[m], v[1], accu[m][1]);
    }
    __builtin_amdgcn_s_setprio(0);
    SCHED0();
    asm volatile("s_waitcnt lgkmcnt(0)" ::: "memory");
    SBAR();
    // P2: kk1 x W
    SCHED0();
    LDA8(a, cur, cb1); LDW2(w, cur, cb1);
    __builtin_amdgcn_s_setprio(1);
#pragma unroll
    for (int m = 0; m < 8; ++m) {
      accg[m][0] = MFMA16(a[m], w[0], accg[m][0]);
      accg[m][1] = MFMA16(a[m], w[1], accg[m][1]);
    }
    __builtin_amdgcn_s_setprio(0);
    SCHED0();
    asm volatile("s_waitcnt lgkmcnt(0)" ::: "memory");
    SBAR();
    // P3: kk1 x V
    SCHED0();
    LDV2(v, cur, cb1);
    __builtin_amdgcn_s_setprio(1);
#pragma unroll
    for (int m = 0; m < 8; ++m) {
      accu[m][0] = MFMA16(a[m], v[0], accu[m][0]);
      accu[m][1] = MFMA16(a[m], v[1], accu[m][1]);
    }
    __builtin_amdgcn_s_setprio(0);
    SCHED0();
    asm volatile("s_waitcnt lgkmcnt(0)" ::: "memory");
    SBAR();
  }
  // epilogue: silu(g)*u -> bf16. C/D map: col=lane&15, row=(lane>>4)*4+r (m89)
  const int r0 = (lane >> 4) * 4;
#pragma unroll
  for (int m = 0; m < 8; ++m)
#pragma unroll
    for (int n = 0; n < 2; ++n)
#pragma unroll
      for (int r = 0; r < 4; ++r) {
        const float g = accg[m][n][r];
        const float u = accu[m][n][r];
        const float s = g / (1.0f + __expf(-g));
        const int row = bm * 256 + wm * 128 + m * 16 + r0 + r;
        const int col = bn * 128 + wn * 32 + n * 16 + l15;
        Inter[(long)row * FFN + col] = f2b(s * u);
      }
}

// ============ down GEMM-BT, 8-phase: 256x256, BK=64, 8 waves ============
__global__ __launch_bounds__(512, 2)
void down256_kernel(const unsigned short* __restrict__ Inter,
                    const unsigned short* __restrict__ W2t,
                    float* __restrict__ Out) {
  __shared__ unsigned short sh[65536];
  const int tid = threadIdx.x, lane = tid & 63, wid = tid >> 6;
  const int wm = wid >> 2, wn = wid & 3;
  const int swz = xcd_chunk(blockIdx.x, (TOKENS / 256) * (HIDDEN / 256));  // 256
  const int bm = swz & 15;
  const int bn = swz >> 4;
  const int sr = tid >> 3;
  const int scb = (((tid & 7) ^ (sr & 7)) << 4);
  const int l15 = lane & 15;
  const int cb0 = (((lane >> 4) * 16) ^ ((lane & 7) << 4));
  const int cb1 = ((64 + (lane >> 4) * 16) ^ ((lane & 7) << 4));

  const unsigned short* Ap = Inter + (long)(bm * 256) * FFN;
  const unsigned short* Bp = W2t + (long)(bn * 256) * FFN;

  f32x4 acc[8][4] = {};

  auto STAGE = [&](int kind, int h, int buf, int t) {
    const unsigned short* src = (kind ? Bp : Ap) + (long)(h * 128 + sr) * FFN + t * 64 + (scb >> 1);
    unsigned short* dst = sh + buf * 32768 + kind * 16384 + h * 8192 + tid * 8;
    __builtin_amdgcn_global_load_lds((gbl_void_t*)src, (lds_void_t*)dst, 16, 0, 0);
    __builtin_amdgcn_global_load_lds((gbl_void_t*)(src + 64L * FFN), (lds_void_t*)(dst + 4096), 16, 0, 0);
  };
  auto LDA8 = [&](bf16x8* a, int buf, int cb) {
    const char* base = (const char*)sh + buf * 65536 + wm * 16384 + l15 * 128 + cb;
#pragma unroll
    for (int m = 0; m < 8; ++m) a[m] = *(const bf16x8*)(base + m * 2048);
  };
  auto LDB2 = [&](bf16x8* b, int buf, int cb, int np) {
    const char* base = (const char*)sh + buf * 65536 + 32768 + (wn >> 1) * 16384 +
                       ((wn & 1) * 64 + l15) * 128 + cb;
    b[2 * np]     = *(const bf16x8*)(base + (2 * np) * 2048);
    b[2 * np + 1] = *(const bf16x8*)(base + (2 * np + 1) * 2048);
  };

  STAGE(0, 0, 0, 0); STAGE(0, 1, 0, 0); STAGE(1, 0, 0, 0); STAGE(1, 1, 0, 0);

  bf16x8 a[8], b[4];
  const int NT = FFN / 64;  // 224
  for (int t = 0; t < NT; ++t) {
    const int cur = t & 1, nxt = cur ^ 1;
    const bool pre = (t + 1 < NT);
    // P0: prefetch B(t+1); gate vmcnt(4); MFMA n01 kk0
    if (pre) { STAGE(1, 0, nxt, t + 1); STAGE(1, 1, nxt, t + 1);
               asm volatile("s_waitcnt vmcnt(4)" ::: "memory"); }
    else     { asm volatile("s_waitcnt vmcnt(0)" ::: "memory"); }
    SBAR(); SCHED0();
    LDA8(a, cur, cb0); LDB2(b, cur, cb0, 0);
    __builtin_amdgcn_s_setprio(1);
#pragma unroll
    for (int m = 0; m < 8; ++m) {
      acc[m][0] = MFMA16(a[m], b[0], acc[m][0]);
      acc[m][1] = MFMA16(a[m], b[1], acc[m][1]);
    }
    __builtin_amdgcn_s_setprio(0);
    SCHED0();
    asm volatile("s_waitcnt lgkmcnt(0)" ::: "memory");
    SBAR();
    // P1: prefetch A(t+1); MFMA n23 kk0
    if (pre) { STAGE(0, 0, nxt, t + 1); STAGE(0, 1, nxt, t + 1); }
    SCHED0();
    LDB2(b, cur, cb0, 1);
    __builtin_amdgcn_s_setprio(1);
#pragma unroll
    for (int m = 0; m < 8; ++m) {
      acc[m][2] = MFMA16(a[m], b[2], acc[m][2]);
      acc[m][3] = MFMA16(a[m], b[3], acc[m][3]);
    }
    __builtin_amdgcn_s_setprio(0);
    SCHED0();
    asm volatile("s_waitcnt lgkmcnt(0)" ::: "memory");
    SBAR();
    // P2: MFMA n01 kk1
    SCHED0();
    LDA8(a, cur, cb1); LDB2(b, cur, cb1, 0);
    __builtin_amdgcn_s_setprio(1);
#pragma unroll
    for (int m = 0; m < 8; ++m) {
      acc[m][0] = MFMA16(a[m], b[0], acc[m][0]);
      acc[m][1] = MFMA16(a[m], b[1], acc[m][1]);
    }
    __builtin_amdgcn_s_setprio(0);
    SCHED0();
    asm volatile("s_waitcnt lgkmcnt(0)" ::: "memory");
    SBAR();
    // P3: MFMA n23 kk1
    SCHED0();
    LDB2(b, cur, cb1, 1);
    __builtin_amdgcn_s_setprio(1);
#pragma unroll
    for (int m = 0; m < 8; ++m) {
      acc[m][2] = MFMA16(a[m], b[2], acc[m][2]);
      acc[m][3] = MFMA16(a[m], b[3], acc[m][3]);
    }
    __builtin_amdgcn_s_setprio(0);
    SCHED0();
    asm volatile("s_waitcnt lgkmcnt(0)" ::: "memory");
    SBAR();
  }
  const int r0 = (lane >> 4) * 4;
#pragma unroll
  for (int m = 0; m < 8; ++m)
#pragma unroll
    for (int n = 0; n < 4; ++n)
#pragma unroll
      for (int r = 0; r < 4; ++r) {
        const int row = bm * 256 + wm * 128 + m * 16 + r0 + r;
        const int col = bn * 256 + wn * 64 + n * 16 + l15;
        Out[(long)row * HIDDEN + col] = acc[m][n][r];
      }
}

// ---- fallback down (round-2 verified) when ws lacks w2t space ----
__device__ __forceinline__ void stage_tile_128(const unsigned short* __restrict__ g, long ldk,
                                               unsigned short* lds, int wave, int lane) {
#pragma unroll
  for (int it = 0; it < 2; ++it) {
    const int row = (it * 4 + wave) * 16 + (lane >> 2);
    const int kcol = (lane & 3) * 8;
    const unsigned short* src = g + (long)row * ldk + kcol;
    unsigned short* dst = lds + row * 32 + kcol;
    __builtin_amdgcn_global_load_lds((gbl_void_t*)src, (lds_void_t*)dst, 16, 0, 0);
  }
}

__global__ __launch_bounds__(256, 2)
void down_nt_kernel(const unsigned short* __restrict__ Inter,
                    const float* __restrict__ W2,
                    float* __restrict__ Out) {
  __shared__ unsigned short As[128 * 32];
  __shared__ unsigned short Bs[128 * 32];
  const int t = threadIdx.x;
  const int lane = t & 63;
  const int wave = t >> 6;
  const int bm = blockIdx.x & 31;
  const int bn = blockIdx.x >> 5;
  const int wm = (wave >> 1) * 64;
  const int wn = (wave & 1) * 64;
  const unsigned short* gA = Inter + (long)(bm * 128) * FFN;

  f32x4 acc[4][4] = {};
  const int fr = lane & 15;
  const int kg = (lane >> 4) * 8;
  const int p = lane & 15;
  const int h0 = wave * 32 + (lane >> 4) * 8;
  const float* gB = W2 + bn * 128 + h0;

  for (int kt = 0; kt < FFN; kt += 32) {
    __syncthreads();
    stage_tile_128(gA + kt, FFN, As, wave, lane);
    const float* r0p = gB + (long)(kt + 2 * p) * HIDDEN;
    const float* r1p = r0p + HIDDEN;
    const float4 a0 = *reinterpret_cast<const float4*>(r0p);
    const float4 a1 = *reinterpret_cast<const float4*>(r0p + 4);
    const float4 b0 = *reinterpret_cast<const float4*>(r1p);
    const float4 b1 = *reinterpret_cast<const float4*>(r1p + 4);
    unsigned short lo[8], hi[8];
    lo[0] = f2b(a0.x); lo[1] = f2b(a0.y); lo[2] = f2b(a0.z); lo[3] = f2b(a0.w);
    lo[4] = f2b(a1.x); lo[5] = f2b(a1.y); lo[6] = f2b(a1.z); lo[7] = f2b(a1.w);
    hi[0] = f2b(b0.x); hi[1] = f2b(b0.y); hi[2] = f2b(b0.z); hi[3] = f2b(b0.w);
    hi[4] = f2b(b1.x); hi[5] = f2b(b1.y); hi[6] = f2b(b1.z); hi[7] = f2b(b1.w);
#pragma unroll
    for (int j = 0; j < 8; ++j) {
      const unsigned int pack = (unsigned int)lo[j] | ((unsigned int)hi[j] << 16);
      *reinterpret_cast<unsigned int*>(&Bs[(h0 + j) * 32 + 2 * p]) = pack;
    }
    __syncthreads();
    bf16x8 a[4], b[4];
#pragma unroll
    for (int m = 0; m < 4; ++m)
      a[m] = *reinterpret_cast<const bf16x8*>(&As[(wm + m * 16 + fr) * 32 + kg]);
#pragma unroll
    for (int n = 0; n < 4; ++n)
      b[n] = *reinterpret_cast<const bf16x8*>(&Bs[(wn + n * 16 + fr) * 32 + kg]);
#pragma unroll
    for (int m = 0; m < 4; ++m)
#pragma unroll
      for (int n = 0; n < 4; ++n)
        acc[m][n] = MFMA16(a[m], b[n], acc[m][n]);
  }
  const int r0 = (lane >> 4) * 4;
#pragma unroll
  for (int m = 0; m < 4; ++m)
#pragma unroll
    for (int n = 0; n < 4; ++n)
#pragma unroll
      for (int r = 0; r < 4; ++r) {
        const int row = bm * 128 + wm + m * 16 + r0 + r;
        const int col = bn * 128 + wn + n * 16 + fr;
        Out[(long)row * HIDDEN + col] = acc[m][n][r];
      }
}

extern "C" void kernel_launch(void* const* d_in, const int* in_sizes, int n_in,
                              void* d_out, int out_size, void* d_ws, size_t ws_size,
                              hipStream_t stream) {
  const float* x  = (const float*)d_in[0];
  const float* w1 = (const float*)d_in[1];
  const float* v1 = (const float*)d_in[2];
  const float* w2 = (const float*)d_in[3];
  float* out = (float*)d_out;

  // ws layout (bytes): xb 33,554,432 | w1b 117,440,512 | v1b 117,440,512 |
  //                    inter 117,440,512 | w2t 117,440,512  -> 503,316,480 total.
  const size_t REQ_SMALL = 385875968UL;
  const size_t REQ_FULL  = 503316480UL;
  if (ws_size < REQ_SMALL) return;
  const bool full = (ws_size >= REQ_FULL);
  char* ws = (char*)d_ws;
  unsigned short* xb     = (unsigned short*)(ws);
  unsigned short* w1b    = (unsigned short*)(ws + 33554432L);
  unsigned short* v1b    = (unsigned short*)(ws + 150994944L);
  unsigned short* interb = (unsigned short*)(ws + 268435456L);
  unsigned short* w2tb   = (unsigned short*)(ws + 385875968L);

  hipLaunchKernelGGL(cvt_kernel, dim3(2048), dim3(256), 0, stream, x,  xb,  (long)TOKENS * HIDDEN);
  hipLaunchKernelGGL(cvt_kernel, dim3(2048), dim3(256), 0, stream, w1, w1b, (long)FFN * HIDDEN);
  hipLaunchKernelGGL(cvt_kernel, dim3(2048), dim3(256), 0, stream, v1, v1b, (long)FFN * HIDDEN);
  if (full)
    hipLaunchKernelGGL(transpose_cvt_kernel, dim3(FFN / 64, HIDDEN / 64), dim3(256), 0, stream, w2, w2tb);
  hipLaunchKernelGGL(gateup256_kernel, dim3((TOKENS / 256) * (FFN / 128)), dim3(512), 0, stream,
                     xb, w1b, v1b, interb);
  if (full)
    hipLaunchKernelGGL(down256_kernel, dim3((TOKENS / 256) * (HIDDEN / 256)), dim3(512), 0, stream,
                       interb, w2tb, out);
  else
    hipLaunchKernelGGL(down_nt_kernel, dim3((TOKENS / 128) * (HIDDEN / 128)), dim3(256), 0, stream,
                       interb, w2, out);
}

// Round 11
// 1420.520 us; speedup vs baseline: 1.1086x; 1.0078x over previous
//
#include <hip/hip_runtime.h>
#include <hip/hip_bf16.h>
#include <stdint.h>

// DbrxExpertGLU: down = (silu(x@w1^T) * (x@v1^T)) @ w2
// T=4096, H=4096, F=14336. fp32 in/out; bf16 MFMA compute.
// R11: gateup made SINGLE-ROUND PERSISTENT — grid 256 (1 block/CU, 1 dispatch
// round), each block loops its 7 F-tiles. Kills the 6 extra round boundaries
// (synchronized cold prologues with nothing to overlap at 1 block/CU).
// K-loop body identical to R10. down256 (already 1 round) unchanged.
#define TOKENS 4096
#define HIDDEN 4096
#define FFN    14336

typedef __attribute__((ext_vector_type(8))) short bf16x8;
typedef __attribute__((ext_vector_type(4))) float f32x4;
typedef __attribute__((ext_vector_type(8))) unsigned short u16x8;

typedef __attribute__((address_space(3))) void lds_void_t;
typedef const __attribute__((address_space(1))) void gbl_void_t;

static __device__ __forceinline__ unsigned short f2b(float f) {
  union { float f; unsigned int u; } v; v.f = f;
  unsigned int u = v.u;
  return (unsigned short)((u + 0x7FFFu + ((u >> 16) & 1u)) >> 16);  // RNE
}

// ---------------- fp32 -> bf16 convert ----------------
__global__ void cvt_kernel(const float* __restrict__ in, unsigned short* __restrict__ out, long n) {
  long idx = (long)blockIdx.x * blockDim.x + threadIdx.x;
  long stride = (long)gridDim.x * blockDim.x;
  for (long i = idx * 4; i < n; i += stride * 4) {
    const float4 v = *reinterpret_cast<const float4*>(in + i);
    ushort4 o;
    o.x = f2b(v.x); o.y = f2b(v.y); o.z = f2b(v.z); o.w = f2b(v.w);
    *reinterpret_cast<ushort4*>(out + i) = o;
  }
}

// ------- w2 [F][H] fp32 -> w2t [H][F] bf16 -------
__global__ void transpose_cvt_kernel(const float* __restrict__ in, unsigned short* __restrict__ out) {
  __shared__ float tile[64][65];
  const int f0 = blockIdx.x * 64;
  const int h0 = blockIdx.y * 64;
  const int t = threadIdx.x;
  const int rcol = (t & 15) * 4;
  const int rrow = t >> 4;
#pragma unroll
  for (int it = 0; it < 4; ++it) {
    int r = rrow + it * 16;
    const float4 v = *reinterpret_cast<const float4*>(in + (long)(f0 + r) * HIDDEN + h0 + rcol);
    tile[r][rcol] = v.x; tile[r][rcol + 1] = v.y; tile[r][rcol + 2] = v.z; tile[r][rcol + 3] = v.w;
  }
  __syncthreads();
  const int wrow = t >> 2;
  const int wc = (t & 3) * 16;
  u16x8 lo, hi;
#pragma unroll
  for (int j = 0; j < 8; ++j) lo[j] = f2b(tile[wc + j][wrow]);
#pragma unroll
  for (int j = 0; j < 8; ++j) hi[j] = f2b(tile[wc + 8 + j][wrow]);
  u16x8* dst = reinterpret_cast<u16x8*>(out + (long)(h0 + wrow) * FFN + f0 + wc);
  dst[0] = lo; dst[1] = hi;
}

#define MFMA16(a, b, c) __builtin_amdgcn_mfma_f32_16x16x32_bf16((a), (b), (c), 0, 0, 0)
#define SBAR()  __builtin_amdgcn_s_barrier()
#define SCHED0() __builtin_amdgcn_sched_barrier(0)

static __device__ __forceinline__ int xcd_chunk(int bid, int nwg) {
  return (bid & 7) * (nwg >> 3) + (bid >> 3);
}

// ============ persistent fused gate/up: grid 256, 7 F-tiles/block ============
// Per tile: BM=256(T) x BN=128(F), BK=64, 8 waves, 8-phase counted-vmcnt.
// LDS per buf (64KB): A[256][64] @0 | W[128][64] @32K | V[128][64] @48K. x2 dbuf.
__global__ __launch_bounds__(512, 2)
void gateup256p_kernel(const unsigned short* __restrict__ X,
                       const unsigned short* __restrict__ W1,
                       const unsigned short* __restrict__ V1,
                       unsigned short* __restrict__ Inter) {
  __shared__ unsigned short sh[65536];  // 128 KB
  const int tid = threadIdx.x, lane = tid & 63, wid = tid >> 6;
  const int wm = wid >> 2, wn = wid & 3;
  const int p = blockIdx.x;           // 0..255, one block per CU
  const int bm = p & 15;              // T-tile (fixed per block)
  const int bnl = p >> 4;             // bn lane 0..15
  const int sr = tid >> 3;
  const int scb = (((tid & 7) ^ (sr & 7)) << 4);
  const int l15 = lane & 15;
  const int cb0 = (((lane >> 4) * 16) ^ ((lane & 7) << 4));
  const int cb1 = ((64 + (lane >> 4) * 16) ^ ((lane & 7) << 4));

  const unsigned short* Ap = X + (long)(bm * 256) * HIDDEN;

  auto LDA8 = [&](bf16x8* a, int buf, int cb) {
    const char* base = (const char*)sh + buf * 65536 + wm * 16384 + l15 * 128 + cb;
#pragma unroll
    for (int m = 0; m < 8; ++m) a[m] = *(const bf16x8*)(base + m * 2048);
  };
  auto LDW2 = [&](bf16x8* w, int buf, int cb) {
    const char* base = (const char*)sh + buf * 65536 + 32768 + (wn * 32 + l15) * 128 + cb;
    w[0] = *(const bf16x8*)(base);
    w[1] = *(const bf16x8*)(base + 2048);
  };
  auto LDV2 = [&](bf16x8* v, int buf, int cb) {
    const char* base = (const char*)sh + buf * 65536 + 49152 + (wn * 32 + l15) * 128 + cb;
    v[0] = *(const bf16x8*)(base);
    v[1] = *(const bf16x8*)(base + 2048);
  };

  for (int j = 0; j < 7; ++j) {
    const int bn = j * 16 + bnl;      // 16 bm-blocks share panel bn concurrently
    const unsigned short* Wp = W1 + (long)(bn * 128) * HIDDEN;
    const unsigned short* Vp = V1 + (long)(bn * 128) * HIDDEN;

    auto STA = [&](int u, int buf, int t) {
      const unsigned short* src = Ap + (long)(u * 64 + sr) * HIDDEN + t * 64 + (scb >> 1);
      unsigned short* dst = sh + buf * 32768 + u * 4096 + tid * 8;
      __builtin_amdgcn_global_load_lds((gbl_void_t*)src, (lds_void_t*)dst, 16, 0, 0);
    };
    auto STW = [&](int u, int buf, int t) {
      const unsigned short* src = Wp + (long)(u * 64 + sr) * HIDDEN + t * 64 + (scb >> 1);
      unsigned short* dst = sh + buf * 32768 + 16384 + u * 4096 + tid * 8;
      __builtin_amdgcn_global_load_lds((gbl_void_t*)src, (lds_void_t*)dst, 16, 0, 0);
    };
    auto STV = [&](int u, int buf, int t) {
      const unsigned short* src = Vp + (long)(u * 64 + sr) * HIDDEN + t * 64 + (scb >> 1);
      unsigned short* dst = sh + buf * 32768 + 24576 + u * 4096 + tid * 8;
      __builtin_amdgcn_global_load_lds((gbl_void_t*)src, (lds_void_t*)dst, 16, 0, 0);
    };

    f32x4 accg[8][2] = {};
    f32x4 accu[8][2] = {};

    // prologue: tile 0 fully staged into buf0 (prior iter's stores already
    // drained by the vmcnt(0) below; LDS buf0 last read 2 barriers ago)
    STA(0, 0, 0); STA(1, 0, 0); STA(2, 0, 0); STA(3, 0, 0);
    STW(0, 0, 0); STW(1, 0, 0); STV(0, 0, 0); STV(1, 0, 0);

    bf16x8 a[8], w[2], v[2];
    const int NT = HIDDEN / 64;  // 64
    for (int t = 0; t < NT; ++t) {
      const int cur = t & 1, nxt = cur ^ 1;
      const bool pre = (t + 1 < NT);
      // P0: prefetch W+V(t+1); gate vmcnt(4); kk0 x W
      if (pre) { STW(0, nxt, t + 1); STW(1, nxt, t + 1);
                 STV(0, nxt, t + 1); STV(1, nxt, t + 1);
                 asm volatile("s_waitcnt vmcnt(4)" ::: "memory"); }
      else     { asm volatile("s_waitcnt vmcnt(0)" ::: "memory"); }
      SBAR(); SCHED0();
      LDA8(a, cur, cb0); LDW2(w, cur, cb0);
      __builtin_amdgcn_s_setprio(1);
#pragma unroll
      for (int m = 0; m < 8; ++m) {
        accg[m][0] = MFMA16(a[m], w[0], accg[m][0]);
        accg[m][1] = MFMA16(a[m], w[1], accg[m][1]);
      }
      __builtin_amdgcn_s_setprio(0);
      SCHED0();
      asm volatile("s_waitcnt lgkmcnt(0)" ::: "memory");
      SBAR();
      // P1: prefetch A(t+1); kk0 x V
      if (pre) { STA(0, nxt, t + 1); STA(1, nxt, t + 1);
                 STA(2, nxt, t + 1); STA(3, nxt, t + 1); }
      SCHED0();
      LDV2(v, cur, cb0);
      __builtin_amdgcn_s_setprio(1);
#pragma unroll
      for (int m = 0; m < 8; ++m) {
        accu[m][0] = MFMA16(a[m], v[0], accu[m][0]);
        accu[m][1] = MFMA16(a[m], v[1], accu[m][1]);
      }
      __builtin_amdgcn_s_setprio(0);
      SCHED0();
      asm volatile("s_waitcnt lgkmcnt(0)" ::: "memory");
      SBAR();
      // P2: kk1 x W
      SCHED0();
      LDA8(a, cur, cb1); LDW2(w, cur, cb1);
      __builtin_amdgcn_s_setprio(1);
#pragma unroll
      for (int m = 0; m < 8; ++m) {
        accg[m][0] = MFMA16(a[m], w[0], accg[m][0]);
        accg[m][1] = MFMA16(a[m], w[1], accg[m][1]);
      }
      __builtin_amdgcn_s_setprio(0);
      SCHED0();
      asm volatile("s_waitcnt lgkmcnt(0)" ::: "memory");
      SBAR();
      // P3: kk1 x V
      SCHED0();
      LDV2(v, cur, cb1);
      __builtin_amdgcn_s_setprio(1);
#pragma unroll
      for (int m = 0; m < 8; ++m) {
        accu[m][0] = MFMA16(a[m], v[0], accu[m][0]);
        accu[m][1] = MFMA16(a[m], v[1], accu[m][1]);
      }
      __builtin_amdgcn_s_setprio(0);
      SCHED0();
      asm volatile("s_waitcnt lgkmcnt(0)" ::: "memory");
      SBAR();
    }
    // epilogue: silu(g)*u -> bf16. C/D map: col=lane&15, row=(lane>>4)*4+r (m89)
    const int r0 = (lane >> 4) * 4;
#pragma unroll
    for (int m = 0; m < 8; ++m)
#pragma unroll
      for (int n = 0; n < 2; ++n)
#pragma unroll
        for (int r = 0; r < 4; ++r) {
          const float g = accg[m][n][r];
          const float u = accu[m][n][r];
          const float s = g / (1.0f + __expf(-g));
          const int row = bm * 256 + wm * 128 + m * 16 + r0 + r;
          const int col = bn * 128 + wn * 32 + n * 16 + l15;
          Inter[(long)row * FFN + col] = f2b(s * u);
        }
    // drain epilogue stores so the next iteration's vmcnt ledger starts clean
    asm volatile("s_waitcnt vmcnt(0)" ::: "memory");
  }
}

// ============ down GEMM-BT, 8-phase: 256x256, BK=64, 8 waves (1 round) ============
__global__ __launch_bounds__(512, 2)
void down256_kernel(const unsigned short* __restrict__ Inter,
                    const unsigned short* __restrict__ W2t,
                    float* __restrict__ Out) {
  __shared__ unsigned short sh[65536];
  const int tid = threadIdx.x, lane = tid & 63, wid = tid >> 6;
  const int wm = wid >> 2, wn = wid & 3;
  const int swz = xcd_chunk(blockIdx.x, (TOKENS / 256) * (HIDDEN / 256));  // 256
  const int bm = swz & 15;
  const int bn = swz >> 4;
  const int sr = tid >> 3;
  const int scb = (((tid & 7) ^ (sr & 7)) << 4);
  const int l15 = lane & 15;
  const int cb0 = (((lane >> 4) * 16) ^ ((lane & 7) << 4));
  const int cb1 = ((64 + (lane >> 4) * 16) ^ ((lane & 7) << 4));

  const unsigned short* Ap = Inter + (long)(bm * 256) * FFN;
  const unsigned short* Bp = W2t + (long)(bn * 256) * FFN;

  f32x4 acc[8][4] = {};

  auto STAGE = [&](int kind, int h, int buf, int t) {
    const unsigned short* src = (kind ? Bp : Ap) + (long)(h * 128 + sr) * FFN + t * 64 + (scb >> 1);
    unsigned short* dst = sh + buf * 32768 + kind * 16384 + h * 8192 + tid * 8;
    __builtin_amdgcn_global_load_lds((gbl_void_t*)src, (lds_void_t*)dst, 16, 0, 0);
    __builtin_amdgcn_global_load_lds((gbl_void_t*)(src + 64L * FFN), (lds_void_t*)(dst + 4096), 16, 0, 0);
  };
  auto LDA8 = [&](bf16x8* a, int buf, int cb) {
    const char* base = (const char*)sh + buf * 65536 + wm * 16384 + l15 * 128 + cb;
#pragma unroll
    for (int m = 0; m < 8; ++m) a[m] = *(const bf16x8*)(base + m * 2048);
  };
  auto LDB2 = [&](bf16x8* b, int buf, int cb, int np) {
    const char* base = (const char*)sh + buf * 65536 + 32768 + (wn >> 1) * 16384 +
                       ((wn & 1) * 64 + l15) * 128 + cb;
    b[2 * np]     = *(const bf16x8*)(base + (2 * np) * 2048);
    b[2 * np + 1] = *(const bf16x8*)(base + (2 * np + 1) * 2048);
  };

  STAGE(0, 0, 0, 0); STAGE(0, 1, 0, 0); STAGE(1, 0, 0, 0); STAGE(1, 1, 0, 0);

  bf16x8 a[8], b[4];
  const int NT = FFN / 64;  // 224
  for (int t = 0; t < NT; ++t) {
    const int cur = t & 1, nxt = cur ^ 1;
    const bool pre = (t + 1 < NT);
    // P0: prefetch B(t+1); gate vmcnt(4); MFMA n01 kk0
    if (pre) { STAGE(1, 0, nxt, t + 1); STAGE(1, 1, nxt, t + 1);
               asm volatile("s_waitcnt vmcnt(4)" ::: "memory"); }
    else     { asm volatile("s_waitcnt vmcnt(0)" ::: "memory"); }
    SBAR(); SCHED0();
    LDA8(a, cur, cb0); LDB2(b, cur, cb0, 0);
    __builtin_amdgcn_s_setprio(1);
#pragma unroll
    for (int m = 0; m < 8; ++m) {
      acc[m][0] = MFMA16(a[m], b[0], acc[m][0]);
      acc[m][1] = MFMA16(a[m], b[1], acc[m][1]);
    }
    __builtin_amdgcn_s_setprio(0);
    SCHED0();
    asm volatile("s_waitcnt lgkmcnt(0)" ::: "memory");
    SBAR();
    // P1: prefetch A(t+1); MFMA n23 kk0
    if (pre) { STAGE(0, 0, nxt, t + 1); STAGE(0, 1, nxt, t + 1); }
    SCHED0();
    LDB2(b, cur, cb0, 1);
    __builtin_amdgcn_s_setprio(1);
#pragma unroll
    for (int m = 0; m < 8; ++m) {
      acc[m][2] = MFMA16(a[m], b[2], acc[m][2]);
      acc[m][3] = MFMA16(a[m], b[3], acc[m][3]);
    }
    __builtin_amdgcn_s_setprio(0);
    SCHED0();
    asm volatile("s_waitcnt lgkmcnt(0)" ::: "memory");
    SBAR();
    // P2: MFMA n01 kk1
    SCHED0();
    LDA8(a, cur, cb1); LDB2(b, cur, cb1, 0);
    __builtin_amdgcn_s_setprio(1);
#pragma unroll
    for (int m = 0; m < 8; ++m) {
      acc[m][0] = MFMA16(a[m], b[0], acc[m][0]);
      acc[m][1] = MFMA16(a[m], b[1], acc[m][1]);
    }
    __builtin_amdgcn_s_setprio(0);
    SCHED0();
    asm volatile("s_waitcnt lgkmcnt(0)" ::: "memory");
    SBAR();
    // P3: MFMA n23 kk1
    SCHED0();
    LDB2(b, cur, cb1, 1);
    __builtin_amdgcn_s_setprio(1);
#pragma unroll
    for (int m = 0; m < 8; ++m) {
      acc[m][2] = MFMA16(a[m], b[2], acc[m][2]);
      acc[m][3] = MFMA16(a[m], b[3], acc[m][3]);
    }
    __builtin_amdgcn_s_setprio(0);
    SCHED0();
    asm volatile("s_waitcnt lgkmcnt(0)" ::: "memory");
    SBAR();
  }
  const int r0 = (lane >> 4) * 4;
#pragma unroll
  for (int m = 0; m < 8; ++m)
#pragma unroll
    for (int n = 0; n < 4; ++n)
#pragma unroll
      for (int r = 0; r < 4; ++r) {
        const int row = bm * 256 + wm * 128 + m * 16 + r0 + r;
        const int col = bn * 256 + wn * 64 + n * 16 + l15;
        Out[(long)row * HIDDEN + col] = acc[m][n][r];
      }
}

// ---- fallback down (round-2 verified) when ws lacks w2t space ----
__device__ __forceinline__ void stage_tile_128(const unsigned short* __restrict__ g, long ldk,
                                               unsigned short* lds, int wave, int lane) {
#pragma unroll
  for (int it = 0; it < 2; ++it) {
    const int row = (it * 4 + wave) * 16 + (lane >> 2);
    const int kcol = (lane & 3) * 8;
    const unsigned short* src = g + (long)row * ldk + kcol;
    unsigned short* dst = lds + row * 32 + kcol;
    __builtin_amdgcn_global_load_lds((gbl_void_t*)src, (lds_void_t*)dst, 16, 0, 0);
  }
}

__global__ __launch_bounds__(256, 2)
void down_nt_kernel(const unsigned short* __restrict__ Inter,
                    const float* __restrict__ W2,
                    float* __restrict__ Out) {
  __shared__ unsigned short As[128 * 32];
  __shared__ unsigned short Bs[128 * 32];
  const int t = threadIdx.x;
  const int lane = t & 63;
  const int wave = t >> 6;
  const int bm = blockIdx.x & 31;
  const int bn = blockIdx.x >> 5;
  const int wm = (wave >> 1) * 64;
  const int wn = (wave & 1) * 64;
  const unsigned short* gA = Inter + (long)(bm * 128) * FFN;

  f32x4 acc[4][4] = {};
  const int fr = lane & 15;
  const int kg = (lane >> 4) * 8;
  const int p = lane & 15;
  const int h0 = wave * 32 + (lane >> 4) * 8;
  const float* gB = W2 + bn * 128 + h0;

  for (int kt = 0; kt < FFN; kt += 32) {
    __syncthreads();
    stage_tile_128(gA + kt, FFN, As, wave, lane);
    const float* r0p = gB + (long)(kt + 2 * p) * HIDDEN;
    const float* r1p = r0p + HIDDEN;
    const float4 a0 = *reinterpret_cast<const float4*>(r0p);
    const float4 a1 = *reinterpret_cast<const float4*>(r0p + 4);
    const float4 b0 = *reinterpret_cast<const float4*>(r1p);
    const float4 b1 = *reinterpret_cast<const float4*>(r1p + 4);
    unsigned short lo[8], hi[8];
    lo[0] = f2b(a0.x); lo[1] = f2b(a0.y); lo[2] = f2b(a0.z); lo[3] = f2b(a0.w);
    lo[4] = f2b(a1.x); lo[5] = f2b(a1.y); lo[6] = f2b(a1.z); lo[7] = f2b(a1.w);
    hi[0] = f2b(b0.x); hi[1] = f2b(b0.y); hi[2] = f2b(b0.z); hi[3] = f2b(b0.w);
    hi[4] = f2b(b1.x); hi[5] = f2b(b1.y); hi[6] = f2b(b1.z); hi[7] = f2b(b1.w);
#pragma unroll
    for (int j = 0; j < 8; ++j) {
      const unsigned int pack = (unsigned int)lo[j] | ((unsigned int)hi[j] << 16);
      *reinterpret_cast<unsigned int*>(&Bs[(h0 + j) * 32 + 2 * p]) = pack;
    }
    __syncthreads();
    bf16x8 a[4], b[4];
#pragma unroll
    for (int m = 0; m < 4; ++m)
      a[m] = *reinterpret_cast<const bf16x8*>(&As[(wm + m * 16 + fr) * 32 + kg]);
#pragma unroll
    for (int n = 0; n < 4; ++n)
      b[n] = *reinterpret_cast<const bf16x8*>(&Bs[(wn + n * 16 + fr) * 32 + kg]);
#pragma unroll
    for (int m = 0; m < 4; ++m)
#pragma unroll
      for (int n = 0; n < 4; ++n)
        acc[m][n] = MFMA16(a[m], b[n], acc[m][n]);
  }
  const int r0 = (lane >> 4) * 4;
#pragma unroll
  for (int m = 0; m < 4; ++m)
#pragma unroll
    for (int n = 0; n < 4; ++n)
#pragma unroll
      for (int r = 0; r < 4; ++r) {
        const int row = bm * 128 + wm + m * 16 + r0 + r;
        const int col = bn * 128 + wn + n * 16 + fr;
        Out[(long)row * HIDDEN + col] = acc[m][n][r];
      }
}

extern "C" void kernel_launch(void* const* d_in, const int* in_sizes, int n_in,
                              void* d_out, int out_size, void* d_ws, size_t ws_size,
                              hipStream_t stream) {
  const float* x  = (const float*)d_in[0];
  const float* w1 = (const float*)d_in[1];
  const float* v1 = (const float*)d_in[2];
  const float* w2 = (const float*)d_in[3];
  float* out = (float*)d_out;

  // ws layout (bytes): xb 33,554,432 | w1b 117,440,512 | v1b 117,440,512 |
  //                    inter 117,440,512 | w2t 117,440,512  -> 503,316,480 total.
  const size_t REQ_SMALL = 385875968UL;
  const size_t REQ_FULL  = 503316480UL;
  if (ws_size < REQ_SMALL) return;
  const bool full = (ws_size >= REQ_FULL);
  char* ws = (char*)d_ws;
  unsigned short* xb     = (unsigned short*)(ws);
  unsigned short* w1b    = (unsigned short*)(ws + 33554432L);
  unsigned short* v1b    = (unsigned short*)(ws + 150994944L);
  unsigned short* interb = (unsigned short*)(ws + 268435456L);
  unsigned short* w2tb   = (unsigned short*)(ws + 385875968L);

  hipLaunchKernelGGL(cvt_kernel, dim3(2048), dim3(256), 0, stream, x,  xb,  (long)TOKENS * HIDDEN);
  hipLaunchKernelGGL(cvt_kernel, dim3(2048), dim3(256), 0, stream, w1, w1b, (long)FFN * HIDDEN);
  hipLaunchKernelGGL(cvt_kernel, dim3(2048), dim3(256), 0, stream, v1, v1b, (long)FFN * HIDDEN);
  if (full)
    hipLaunchKernelGGL(transpose_cvt_kernel, dim3(FFN / 64, HIDDEN / 64), dim3(256), 0, stream, w2, w2tb);
  hipLaunchKernelGGL(gateup256p_kernel, dim3(256), dim3(512), 0, stream,
                     xb, w1b, v1b, interb);
  if (full)
    hipLaunchKernelGGL(down256_kernel, dim3((TOKENS / 256) * (HIDDEN / 256)), dim3(512), 0, stream,
                       interb, w2tb, out);
  else
    hipLaunchKernelGGL(down_nt_kernel, dim3((TOKENS / 128) * (HIDDEN / 128)), dim3(256), 0, stream,
                       interb, w2, out);
}